// Round 1
// baseline (436.981 us; speedup 1.0000x reference)
//
#include <hip/hip_runtime.h>

// Dense image warp (bilinear), tfa.dense_image_warp semantics.
// image: (N,H,W,C) fp32, flow: (N,H,W,2) fp32, out: (N,H,W,C) fp32
// N=8, H=512, W=512, C=32.
//
// Layout: one thread per (pixel, float4-channel-chunk). C=32 -> C4=8 chunks.
// Consecutive threads: chunk varies fastest -> coalesced 128B per pixel.

#define C_CH   32
#define C4_CH  8   // C/4

__global__ __launch_bounds__(256) void dense_warp_kernel(
    const float* __restrict__ image,
    const float* __restrict__ flow,
    float* __restrict__ out,
    int H, int W, int total_threads) {
  int tid = blockIdx.x * blockDim.x + threadIdx.x;
  if (tid >= total_threads) return;

  int c4  = tid & (C4_CH - 1);     // chunk within pixel
  int pix = tid >> 3;              // (n*H + h)*W + w
  int w   = pix & (W - 1);         // W = 512, pow2
  int nh  = pix >> 9;              // / W
  int h   = nh & (H - 1);          // H = 512, pow2

  // flow: (pix, 2) -> [dy, dx]
  float2 fl = ((const float2*)flow)[pix];
  float qy = (float)h - fl.x;
  float qx = (float)w - fl.y;

  float fy_f = fminf(fmaxf(floorf(qy), 0.0f), (float)(H - 2));
  float fx_f = fminf(fmaxf(floorf(qx), 0.0f), (float)(W - 2));
  float ay = fminf(fmaxf(qy - fy_f, 0.0f), 1.0f);
  float ax = fminf(fmaxf(qx - fx_f, 0.0f), 1.0f);
  int fy = (int)fy_f;
  int fx = (int)fx_f;

  // image as float4: ((n*H + y)*W + x)*C4 + c4
  const float4* img4 = (const float4*)image;
  int n_base = (pix >> 18) * (H * W);        // n*H*W  (pix/(H*W)); H*W = 2^18
  int row0 = (n_base + ((h - h) /*0*/ + 0)) ; // placeholder removed below
  (void)row0;
  int idx_tl = ((n_base + fy * W + fx) << 3) + c4;   // *C4 (=8) -> <<3
  int idx_tr = idx_tl + C4_CH;                        // fx+1
  int idx_bl = idx_tl + (W << 3);                     // fy+1
  int idx_br = idx_bl + C4_CH;

  float4 tl = img4[idx_tl];
  float4 tr = img4[idx_tr];
  float4 bl = img4[idx_bl];
  float4 br = img4[idx_br];

  float4 r;
  {
    float top = tl.x + ax * (tr.x - tl.x);
    float bot = bl.x + ax * (br.x - bl.x);
    r.x = top + ay * (bot - top);
  }
  {
    float top = tl.y + ax * (tr.y - tl.y);
    float bot = bl.y + ax * (br.y - bl.y);
    r.y = top + ay * (bot - top);
  }
  {
    float top = tl.z + ax * (tr.z - tl.z);
    float bot = bl.z + ax * (br.z - bl.z);
    r.z = top + ay * (bot - top);
  }
  {
    float top = tl.w + ax * (tr.w - tl.w);
    float bot = bl.w + ax * (br.w - bl.w);
    r.w = top + ay * (bot - top);
  }

  ((float4*)out)[tid] = r;
}

extern "C" void kernel_launch(void* const* d_in, const int* in_sizes, int n_in,
                              void* d_out, int out_size, void* d_ws, size_t ws_size,
                              hipStream_t stream) {
  const float* image = (const float*)d_in[0];
  const float* flow  = (const float*)d_in[1];
  float* out = (float*)d_out;

  const int N = 8, H = 512, W = 512;
  int total = N * H * W * C4_CH;           // 16,777,216 threads
  int block = 256;
  int grid = (total + block - 1) / block;  // 65,536 blocks
  dense_warp_kernel<<<grid, block, 0, stream>>>(image, flow, out, H, W, total);
}